// Round 7
// baseline (1850.069 us; speedup 1.0000x reference)
//
#include <hip/hip_runtime.h>

#define B_DIM 16
#define L_DIM 1024
#define D_DIM 512
#define H_DIM 256
#define K_DIM 4

#define SLICES 8        // wgs per batch
#define RPW 32          // rows per wg (H_DIM / SLICES)

// ---------------- workspace layout (bytes) ----------------
#define OFF_HB  0                      // u64 hb[2][16][256] (tag<<32 | f32 bits), 64KB
#define OFF_SEL 65536                  // float SEL[16384*4]
#define OFF_RN  327680                 // float rN[16384*256]

__device__ __forceinline__ float fast_log2(float x) { return __builtin_amdgcn_logf(x); }
__device__ __forceinline__ float fast_exp2(float x) { return __builtin_amdgcn_exp2f(x); }

// LDS column swizzle: XOR chunk bits into bank bits [4:2]; keeps 16B blocks
// contiguous. swz is an involution (swz(swz(j)) == j).
__device__ __forceinline__ int swz(int j) { return j ^ (((j >> 5) & 7) << 2); }

// ---------------- init: zero tagged h state (tag=0, h=0) ----------------
__global__ void k_init(unsigned long long* hb) {
    int tid = blockIdx.x * blockDim.x + threadIdx.x;
    for (int i = tid; i < 2 * 16 * 256; i += 512) hb[i] = 0ull;
}

// ---------------- selector GEMM + softmax ----------------
__global__ __launch_bounds__(256) void k_sel(const float* __restrict__ x,
                                             const float* __restrict__ Wsel,
                                             const float* __restrict__ bsel,
                                             float* __restrict__ SEL) {
    int row  = blockIdx.x * 4 + (threadIdx.x >> 6);
    int lane = threadIdx.x & 63;
    const float4* x4 = (const float4*)(x + (size_t)row * D_DIM);
    const float4* w4 = (const float4*)Wsel;
    float4 xa = x4[lane * 2], xb = x4[lane * 2 + 1];
    float acc[4];
#pragma unroll
    for (int k = 0; k < 4; ++k) {
        float4 wa = w4[k * (D_DIM / 4) + lane * 2];
        float4 wb = w4[k * (D_DIM / 4) + lane * 2 + 1];
        acc[k] = xa.x * wa.x + xa.y * wa.y + xa.z * wa.z + xa.w * wa.w +
                 xb.x * wb.x + xb.y * wb.y + xb.z * wb.z + xb.w * wb.w;
    }
#pragma unroll
    for (int off = 1; off < 64; off <<= 1) {
#pragma unroll
        for (int k = 0; k < 4; ++k) acc[k] += __shfl_xor(acc[k], off, 64);
    }
    if (lane == 0) {
        float z[4], mx = -1e30f;
#pragma unroll
        for (int k = 0; k < 4; ++k) { z[k] = acc[k] + bsel[k]; mx = fmaxf(mx, z[k]); }
        float e[4], s = 0.0f;
#pragma unroll
        for (int k = 0; k < 4; ++k) { e[k] = fast_exp2((z[k] - mx) * 1.4426950408889634f); s += e[k]; }
        float inv = 1.0f / s;
        float4 o = { e[0] * inv, e[1] * inv, e[2] * inv, e[3] * inv };
        ((float4*)SEL)[row] = o;
    }
}

// ---------------- U = X @ W_B^T (f32 tiled GEMM), written into d_out ----------------
#define GBM 64
#define GBN 64
#define GBK 32
__global__ __launch_bounds__(256) void k_u(const float* __restrict__ X,
                                           const float* __restrict__ W,
                                           float* __restrict__ U) {
    __shared__ float Xs[GBK][GBM + 1];
    __shared__ float Ws[GBK][GBN + 1];
    int tid = threadIdx.x;
    int rb = blockIdx.y * GBM;
    int cb = blockIdx.x * GBN;
    int tr = tid >> 4, tc = tid & 15;
    int lrow = tid >> 2;
    int lcol = (tid & 3) * 8;
    float acc[4][4] = {};
    for (int kt = 0; kt < D_DIM; kt += GBK) {
        float4 xa = *(const float4*)(X + (size_t)(rb + lrow) * D_DIM + kt + lcol);
        float4 xb = *(const float4*)(X + (size_t)(rb + lrow) * D_DIM + kt + lcol + 4);
        float4 wa = *(const float4*)(W + (size_t)(cb + lrow) * D_DIM + kt + lcol);
        float4 wb = *(const float4*)(W + (size_t)(cb + lrow) * D_DIM + kt + lcol + 4);
        __syncthreads();
        Xs[lcol + 0][lrow] = xa.x; Xs[lcol + 1][lrow] = xa.y;
        Xs[lcol + 2][lrow] = xa.z; Xs[lcol + 3][lrow] = xa.w;
        Xs[lcol + 4][lrow] = xb.x; Xs[lcol + 5][lrow] = xb.y;
        Xs[lcol + 6][lrow] = xb.z; Xs[lcol + 7][lrow] = xb.w;
        Ws[lcol + 0][lrow] = wa.x; Ws[lcol + 1][lrow] = wa.y;
        Ws[lcol + 2][lrow] = wa.z; Ws[lcol + 3][lrow] = wa.w;
        Ws[lcol + 4][lrow] = wb.x; Ws[lcol + 5][lrow] = wb.y;
        Ws[lcol + 6][lrow] = wb.z; Ws[lcol + 7][lrow] = wb.w;
        __syncthreads();
#pragma unroll
        for (int kk = 0; kk < GBK; ++kk) {
            float a0 = Xs[kk][tr * 4 + 0], a1 = Xs[kk][tr * 4 + 1];
            float a2 = Xs[kk][tr * 4 + 2], a3 = Xs[kk][tr * 4 + 3];
            float b0 = Ws[kk][tc * 4 + 0], b1 = Ws[kk][tc * 4 + 1];
            float b2 = Ws[kk][tc * 4 + 2], b3 = Ws[kk][tc * 4 + 3];
            acc[0][0] = fmaf(a0, b0, acc[0][0]); acc[0][1] = fmaf(a0, b1, acc[0][1]);
            acc[0][2] = fmaf(a0, b2, acc[0][2]); acc[0][3] = fmaf(a0, b3, acc[0][3]);
            acc[1][0] = fmaf(a1, b0, acc[1][0]); acc[1][1] = fmaf(a1, b1, acc[1][1]);
            acc[1][2] = fmaf(a1, b2, acc[1][2]); acc[1][3] = fmaf(a1, b3, acc[1][3]);
            acc[2][0] = fmaf(a2, b0, acc[2][0]); acc[2][1] = fmaf(a2, b1, acc[2][1]);
            acc[2][2] = fmaf(a2, b2, acc[2][2]); acc[2][3] = fmaf(a2, b3, acc[2][3]);
            acc[3][0] = fmaf(a3, b0, acc[3][0]); acc[3][1] = fmaf(a3, b1, acc[3][1]);
            acc[3][2] = fmaf(a3, b2, acc[3][2]); acc[3][3] = fmaf(a3, b3, acc[3][3]);
        }
        __syncthreads();
    }
#pragma unroll
    for (int mi = 0; mi < 4; ++mi) {
        float4 v = { acc[mi][0], acc[mi][1], acc[mi][2], acc[mi][3] };
        *(float4*)(U + (size_t)(rb + tr * 4 + mi) * H_DIM + cb + tc * 4) = v;
    }
}

// ---------------- reciprocal Lp column norms ----------------
__global__ __launch_bounds__(256) void k_norm(const float* __restrict__ M,
                                              const float* __restrict__ SEL,
                                              float* __restrict__ rN) {
    int wg = blockIdx.x;
    int b = wg >> 6;
    int t0 = (wg & 63) << 4;
    int j = threadIdx.x;
    float s[16][4];
#pragma unroll
    for (int tt = 0; tt < 16; ++tt) {
        float4 sv = ((const float4*)SEL)[b * L_DIM + t0 + tt];
        s[tt][0] = sv.x; s[tt][1] = sv.y; s[tt][2] = sv.z; s[tt][3] = sv.w;
    }
    float acc[16] = {};
    const float4* M4 = (const float4*)M;
    for (int i = 0; i < H_DIM; ++i) {
        float4 m = M4[i * H_DIM + j];
#pragma unroll
        for (int tt = 0; tt < 16; ++tt) {
            float a = fmaf(m.x, s[tt][0], fmaf(m.y, s[tt][1],
                      fmaf(m.z, s[tt][2], m.w * s[tt][3])));
            a = fabsf(a);
            acc[tt] += fast_exp2(1.2f * fast_log2(a));  // |a|^1.2
        }
    }
#pragma unroll
    for (int tt = 0; tt < 16; ++tt) {
        rN[(size_t)(b * L_DIM + t0 + tt) * H_DIM + j] =
            fast_exp2(-0.8333333333f * fast_log2(acc[tt]));
    }
}

// ---------------- sequential scan (tagged-word sync, wave-local reduce,
//                   swizzled g_lds) ----------------
// 128 wgs: b = wg&15, slice = wg>>4. Wave q owns rows slice*32+q*8 .. +8;
// lane = chunk*8 + ro: row = base+ro, j in [chunk*32, chunk*32+32).
// g_lds stored XOR-swizzled (swz) so the 8 chunks' ds_read_b128 hit 8
// distinct bank groups (was 8-way conflict in R6). One barrier/step;
// per-row partials reduced with 3x shfl_xor; each wave publishes its own
// 8 rows immediately via tagged 64-bit words.
__global__ __launch_bounds__(256, 1) void k_scan(const float* __restrict__ M,
                                                 const float* __restrict__ SEL,
                                                 const float* __restrict__ rN,
                                                 float* __restrict__ out,
                                                 unsigned long long* hb) {
    const int wg = blockIdx.x;
    const int b = wg & 15;
    const int slice = wg >> 4;
    const int tid = threadIdx.x;
    const int q = tid >> 6;
    const int lane = tid & 63;
    const int ro = lane & 7;
    const int chunk = lane >> 3;
    const int row = slice * RPW + q * 8 + ro;   // row this lane accumulates
    const int jbase = chunk * 32;
    const int wpos = swz(tid);                  // swizzled write slot

    float m[128];
    {
        const float4* M4 = (const float4*)M;
#pragma unroll
        for (int jj = 0; jj < 32; ++jj) {
            float4 v = M4[row * H_DIM + jbase + jj];
            m[jj * 4 + 0] = v.x; m[jj * 4 + 1] = v.y;
            m[jj * 4 + 2] = v.z; m[jj * 4 + 3] = v.w;
        }
    }

    __shared__ float g_lds[2][256];

#pragma unroll 1
    for (int t = 0; t < L_DIM; ++t) {
        // independent loads issued before the poll (latency hidden under it)
        float rn = rN[(size_t)(b * L_DIM + t) * H_DIM + tid];
        float4 s4 = ((const float4*)SEL)[b * L_DIM + t];
        float uval = 0.0f;
        if (lane < 8) uval = out[(size_t)(b * L_DIM + t) * H_DIM + row];

        // poll own tagged word for step t (thread tid <-> column j = tid)
        unsigned long long* src = hb + (size_t)(t & 1) * (16 * 256) + b * 256 + tid;
        unsigned long long w;
        while (((w = __hip_atomic_load(src, __ATOMIC_RELAXED, __HIP_MEMORY_SCOPE_AGENT)) >> 32)
               != (unsigned int)t)
            __builtin_amdgcn_s_sleep(1);
        float h = __uint_as_float((unsigned int)w);
        g_lds[t & 1][wpos] = h * rn;
        __syncthreads();

        float acc0 = 0, acc1 = 0, acc2 = 0, acc3 = 0;
        const float* gbuf = g_lds[t & 1];
#pragma unroll
        for (int jj4 = 0; jj4 < 8; ++jj4) {
            // swizzled read: block jj4 of this chunk lives at bank group jj4^chunk
            float4 gv = *(const float4*)(gbuf + jbase + (((jj4 ^ chunk) & 7) << 2));
            acc0 = fmaf(m[(jj4 * 4 + 0) * 4 + 0], gv.x, acc0);
            acc1 = fmaf(m[(jj4 * 4 + 0) * 4 + 1], gv.x, acc1);
            acc2 = fmaf(m[(jj4 * 4 + 0) * 4 + 2], gv.x, acc2);
            acc3 = fmaf(m[(jj4 * 4 + 0) * 4 + 3], gv.x, acc3);
            acc0 = fmaf(m[(jj4 * 4 + 1) * 4 + 0], gv.y, acc0);
            acc1 = fmaf(m[(jj4 * 4 + 1) * 4 + 1], gv.y, acc1);
            acc2 = fmaf(m[(jj4 * 4 + 1) * 4 + 2], gv.y, acc2);
            acc3 = fmaf(m[(jj4 * 4 + 1) * 4 + 3], gv.y, acc3);
            acc0 = fmaf(m[(jj4 * 4 + 2) * 4 + 0], gv.z, acc0);
            acc1 = fmaf(m[(jj4 * 4 + 2) * 4 + 1], gv.z, acc1);
            acc2 = fmaf(m[(jj4 * 4 + 2) * 4 + 2], gv.z, acc2);
            acc3 = fmaf(m[(jj4 * 4 + 2) * 4 + 3], gv.z, acc3);
            acc0 = fmaf(m[(jj4 * 4 + 3) * 4 + 0], gv.w, acc0);
            acc1 = fmaf(m[(jj4 * 4 + 3) * 4 + 1], gv.w, acc1);
            acc2 = fmaf(m[(jj4 * 4 + 3) * 4 + 2], gv.w, acc2);
            acc3 = fmaf(m[(jj4 * 4 + 3) * 4 + 3], gv.w, acc3);
        }
        // NOTE: with the swizzled read order, block jj4 read is m-block (jj4)
        // in the SAME order as before because we index m by jj4, and the gv
        // fetched corresponds to columns jbase + (jj4^chunk... wait) --
        // the gv block at bank group (jj4^chunk) holds columns
        // jbase + ((jj4^chunk)^chunk)*4 = jbase + jj4*4. m indexing matches.
        float part = fmaf(acc0, s4.x, fmaf(acc1, s4.y, fmaf(acc2, s4.z, acc3 * s4.w)));
        // wave-local reduce over the 8 chunks of this row
        part += __shfl_xor(part, 8, 64);
        part += __shfl_xor(part, 16, 64);
        part += __shfl_xor(part, 32, 64);

        if (lane < 8) {
            float hn = part + uval;   // lane == ro here
            unsigned long long pw = ((unsigned long long)(unsigned int)(t + 1) << 32) |
                                    (unsigned long long)__float_as_uint(hn);
            __hip_atomic_store(hb + (size_t)((t + 1) & 1) * (16 * 256) + b * 256 + row,
                               pw, __ATOMIC_RELAXED, __HIP_MEMORY_SCOPE_AGENT);
            out[(size_t)(b * L_DIM + t) * H_DIM + row] = hn;
        }
    }
}

extern "C" void kernel_launch(void* const* d_in, const int* in_sizes, int n_in,
                              void* d_out, int out_size, void* d_ws, size_t ws_size,
                              hipStream_t stream) {
    const float* x    = (const float*)d_in[0];  // (16,1024,512)
    const float* Wsel = (const float*)d_in[1];  // (4,512)
    const float* bsel = (const float*)d_in[2];  // (4,)
    const float* W_B  = (const float*)d_in[3];  // (256,512)
    const float* M    = (const float*)d_in[4];  // (256,256,4)
    float* out = (float*)d_out;                 // (16,1024,256)

    char* ws = (char*)d_ws;
    unsigned long long* hb = (unsigned long long*)(ws + OFF_HB);
    float* SEL = (float*)(ws + OFF_SEL);
    float* rN  = (float*)(ws + OFF_RN);

    k_init<<<1, 512, 0, stream>>>(hb);
    k_sel<<<(B_DIM * L_DIM) / 4, 256, 0, stream>>>(x, Wsel, bsel, SEL);
    k_u<<<dim3(H_DIM / GBN, (B_DIM * L_DIM) / GBM), 256, 0, stream>>>(x, W_B, out);
    k_norm<<<(B_DIM * L_DIM) / 16, 256, 0, stream>>>(M, SEL, rN);
    k_scan<<<B_DIM * SLICES, 256, 0, stream>>>(M, SEL, rN, out, hb);
}

// Round 8
// 1325.573 us; speedup vs baseline: 1.3957x; 1.3957x over previous
//
#include <hip/hip_runtime.h>

#define B_DIM 16
#define L_DIM 1024
#define D_DIM 512
#define H_DIM 256
#define K_DIM 4

#define SLICES 8        // wgs per batch
#define RPW 32          // rows per wg (H_DIM / SLICES)

// ---------------- workspace layout (bytes) ----------------
#define OFF_HB  0                      // u64 hb[2][16][256] (tag<<32 | f32 bits), 64KB
#define OFF_SEL 65536                  // float SEL[16384*4]
#define OFF_RN  327680                 // float rN[16384*256]

__device__ __forceinline__ float fast_log2(float x) { return __builtin_amdgcn_logf(x); }
__device__ __forceinline__ float fast_exp2(float x) { return __builtin_amdgcn_exp2f(x); }

// ---------------- init: zero tagged h state (tag=0, h=0) ----------------
__global__ void k_init(unsigned long long* hb) {
    int tid = blockIdx.x * blockDim.x + threadIdx.x;
    for (int i = tid; i < 2 * 16 * 256; i += 512) hb[i] = 0ull;
}

// ---------------- fused parallel phase ----------------
// blocks [0,1024): norm-role  -- computes SEL (inline selector+softmax) for
//                  its 16 t's, writes SEL, then rN (Lp column norms).
// blocks [1024,2048): u-role  -- 64x64 f32 GEMM tile of U = X @ W_B^T into out.
// Roles use different pipes (transcendental vs FMA/LDS) -> co-residency overlap.
#define GBM 64
#define GBN 64
#define GBK 32
__global__ __launch_bounds__(256) void k_par(const float* __restrict__ x,
                                             const float* __restrict__ Wsel,
                                             const float* __restrict__ bsel,
                                             const float* __restrict__ W_B,
                                             const float* __restrict__ M,
                                             float* __restrict__ SEL,
                                             float* __restrict__ rN,
                                             float* __restrict__ out) {
    __shared__ float Xs[GBK][GBM + 1];
    __shared__ float Ws[GBK][GBN + 1];
    __shared__ float4 sel_lds[16];
    const int bid = blockIdx.x;
    const int tid = threadIdx.x;

    if (bid < 1024) {
        // ---------- norm role ----------
        const int b = bid >> 6;
        const int t0 = (bid & 63) << 4;
        const int lane = tid & 63;
        const int wv = tid >> 6;
        // inline selector GEMM + softmax: wave wv handles rows wv*4 .. wv*4+3
        const float4* w4 = (const float4*)Wsel;
#pragma unroll
        for (int rr = 0; rr < 4; ++rr) {
            const int tt = wv * 4 + rr;
            const int row = b * L_DIM + t0 + tt;
            const float4* x4 = (const float4*)(x + (size_t)row * D_DIM);
            float4 xa = x4[lane * 2], xb = x4[lane * 2 + 1];
            float acc[4];
#pragma unroll
            for (int k = 0; k < 4; ++k) {
                float4 wa = w4[k * (D_DIM / 4) + lane * 2];
                float4 wb = w4[k * (D_DIM / 4) + lane * 2 + 1];
                acc[k] = xa.x * wa.x + xa.y * wa.y + xa.z * wa.z + xa.w * wa.w +
                         xb.x * wb.x + xb.y * wb.y + xb.z * wb.z + xb.w * wb.w;
            }
#pragma unroll
            for (int off = 1; off < 64; off <<= 1) {
#pragma unroll
                for (int k = 0; k < 4; ++k) acc[k] += __shfl_xor(acc[k], off, 64);
            }
            if (lane == 0) {
                float z[4], mx = -1e30f;
#pragma unroll
                for (int k = 0; k < 4; ++k) { z[k] = acc[k] + bsel[k]; mx = fmaxf(mx, z[k]); }
                float e[4], s = 0.0f;
#pragma unroll
                for (int k = 0; k < 4; ++k) { e[k] = fast_exp2((z[k] - mx) * 1.4426950408889634f); s += e[k]; }
                float inv = 1.0f / s;
                float4 o = { e[0] * inv, e[1] * inv, e[2] * inv, e[3] * inv };
                sel_lds[tt] = o;
                ((float4*)SEL)[row] = o;
            }
        }
        __syncthreads();

        const int j = tid;
        float s[16][4];
#pragma unroll
        for (int tt = 0; tt < 16; ++tt) {
            float4 sv = sel_lds[tt];
            s[tt][0] = sv.x; s[tt][1] = sv.y; s[tt][2] = sv.z; s[tt][3] = sv.w;
        }
        float acc[16] = {};
        const float4* M4 = (const float4*)M;
        for (int i = 0; i < H_DIM; ++i) {
            float4 m = M4[i * H_DIM + j];
#pragma unroll
            for (int tt = 0; tt < 16; ++tt) {
                float a = fmaf(m.x, s[tt][0], fmaf(m.y, s[tt][1],
                          fmaf(m.z, s[tt][2], m.w * s[tt][3])));
                a = fabsf(a);
                acc[tt] += fast_exp2(1.2f * fast_log2(a));  // |a|^1.2
            }
        }
#pragma unroll
        for (int tt = 0; tt < 16; ++tt) {
            rN[(size_t)(b * L_DIM + t0 + tt) * H_DIM + j] =
                fast_exp2(-0.8333333333f * fast_log2(acc[tt]));
        }
    } else {
        // ---------- u role: 64x64 f32 GEMM tile ----------
        const int w = bid - 1024;
        const int cb = (w & 3) * GBN;
        const int rb = (w >> 2) * GBM;
        const int tr = tid >> 4, tc = tid & 15;
        const int lrow = tid >> 2;
        const int lcol = (tid & 3) * 8;
        float acc[4][4] = {};
        for (int kt = 0; kt < D_DIM; kt += GBK) {
            float4 xa = *(const float4*)(x + (size_t)(rb + lrow) * D_DIM + kt + lcol);
            float4 xb = *(const float4*)(x + (size_t)(rb + lrow) * D_DIM + kt + lcol + 4);
            float4 wa = *(const float4*)(W_B + (size_t)(cb + lrow) * D_DIM + kt + lcol);
            float4 wb = *(const float4*)(W_B + (size_t)(cb + lrow) * D_DIM + kt + lcol + 4);
            __syncthreads();
            Xs[lcol + 0][lrow] = xa.x; Xs[lcol + 1][lrow] = xa.y;
            Xs[lcol + 2][lrow] = xa.z; Xs[lcol + 3][lrow] = xa.w;
            Xs[lcol + 4][lrow] = xb.x; Xs[lcol + 5][lrow] = xb.y;
            Xs[lcol + 6][lrow] = xb.z; Xs[lcol + 7][lrow] = xb.w;
            Ws[lcol + 0][lrow] = wa.x; Ws[lcol + 1][lrow] = wa.y;
            Ws[lcol + 2][lrow] = wa.z; Ws[lcol + 3][lrow] = wa.w;
            Ws[lcol + 4][lrow] = wb.x; Ws[lcol + 5][lrow] = wb.y;
            Ws[lcol + 6][lrow] = wb.z; Ws[lcol + 7][lrow] = wb.w;
            __syncthreads();
#pragma unroll
            for (int kk = 0; kk < GBK; ++kk) {
                float a0 = Xs[kk][tr * 4 + 0], a1 = Xs[kk][tr * 4 + 1];
                float a2 = Xs[kk][tr * 4 + 2], a3 = Xs[kk][tr * 4 + 3];
                float b0 = Ws[kk][tc * 4 + 0], b1 = Ws[kk][tc * 4 + 1];
                float b2 = Ws[kk][tc * 4 + 2], b3 = Ws[kk][tc * 4 + 3];
                acc[0][0] = fmaf(a0, b0, acc[0][0]); acc[0][1] = fmaf(a0, b1, acc[0][1]);
                acc[0][2] = fmaf(a0, b2, acc[0][2]); acc[0][3] = fmaf(a0, b3, acc[0][3]);
                acc[1][0] = fmaf(a1, b0, acc[1][0]); acc[1][1] = fmaf(a1, b1, acc[1][1]);
                acc[1][2] = fmaf(a1, b2, acc[1][2]); acc[1][3] = fmaf(a1, b3, acc[1][3]);
                acc[2][0] = fmaf(a2, b0, acc[2][0]); acc[2][1] = fmaf(a2, b1, acc[2][1]);
                acc[2][2] = fmaf(a2, b2, acc[2][2]); acc[2][3] = fmaf(a2, b3, acc[2][3]);
                acc[3][0] = fmaf(a3, b0, acc[3][0]); acc[3][1] = fmaf(a3, b1, acc[3][1]);
                acc[3][2] = fmaf(a3, b2, acc[3][2]); acc[3][3] = fmaf(a3, b3, acc[3][3]);
            }
            __syncthreads();
        }
#pragma unroll
        for (int mi = 0; mi < 4; ++mi) {
            float4 v = { acc[mi][0], acc[mi][1], acc[mi][2], acc[mi][3] };
            *(float4*)(out + (size_t)(rb + tr * 4 + mi) * H_DIM + cb + tc * 4) = v;
        }
    }
}

// ---------------- sequential scan (tagged-word sync, R5 structure) ----------------
// 128 wgs: b = wg&15, slice = wg>>4. Each h element travels as a 64-bit
// word (tag=step)<<32 | f32 bits; a reader's poll IS the data load.
// Two barriers/step; wave 0 publishes all 32 rows as one contiguous burst
// (single 256B store) -- empirically beats per-wave scattered publish (R6/R7).
__global__ __launch_bounds__(256, 1) void k_scan(const float* __restrict__ M,
                                                 const float* __restrict__ SEL,
                                                 const float* __restrict__ rN,
                                                 float* __restrict__ out,
                                                 unsigned long long* hb) {
    const int wg = blockIdx.x;
    const int b = wg & 15;
    const int slice = wg >> 4;
    const int tid = threadIdx.x;
    const int q = tid >> 6;
    const int ti = tid & 63;
    const int r = ti & 31;
    const int js = ti >> 5;
    const int ig = slice * RPW + r;
    const int jbase = q * 64 + js * 32;

    float m[128];
    {
        const float4* M4 = (const float4*)M;
#pragma unroll
        for (int jj = 0; jj < 32; ++jj) {
            float4 v = M4[ig * H_DIM + jbase + jj];
            m[jj * 4 + 0] = v.x; m[jj * 4 + 1] = v.y;
            m[jj * 4 + 2] = v.z; m[jj * 4 + 3] = v.w;
        }
    }

    __shared__ float g_lds[256];
    __shared__ float part_lds[256];

#pragma unroll 1
    for (int t = 0; t < L_DIM; ++t) {
        // independent loads issued before the poll (latency hidden under it)
        float rn = rN[(size_t)(b * L_DIM + t) * H_DIM + tid];
        float4 s4 = ((const float4*)SEL)[b * L_DIM + t];
        float uval = 0.0f;
        if (tid < RPW) uval = out[(size_t)(b * L_DIM + t) * H_DIM + slice * RPW + tid];

        // poll own tagged word for step t (thread tid <-> column j = tid)
        unsigned long long* src = hb + (size_t)(t & 1) * (16 * 256) + b * 256 + tid;
        unsigned long long w;
        while (((w = __hip_atomic_load(src, __ATOMIC_RELAXED, __HIP_MEMORY_SCOPE_AGENT)) >> 32)
               != (unsigned int)t)
            __builtin_amdgcn_s_sleep(1);
        float h = __uint_as_float((unsigned int)w);
        g_lds[tid] = h * rn;
        __syncthreads();

        float acc0 = 0, acc1 = 0, acc2 = 0, acc3 = 0;
        const float4* g4 = (const float4*)(g_lds + jbase);
#pragma unroll
        for (int jj4 = 0; jj4 < 8; ++jj4) {
            float4 gv = g4[jj4];
            acc0 = fmaf(m[(jj4 * 4 + 0) * 4 + 0], gv.x, acc0);
            acc1 = fmaf(m[(jj4 * 4 + 0) * 4 + 1], gv.x, acc1);
            acc2 = fmaf(m[(jj4 * 4 + 0) * 4 + 2], gv.x, acc2);
            acc3 = fmaf(m[(jj4 * 4 + 0) * 4 + 3], gv.x, acc3);
            acc0 = fmaf(m[(jj4 * 4 + 1) * 4 + 0], gv.y, acc0);
            acc1 = fmaf(m[(jj4 * 4 + 1) * 4 + 1], gv.y, acc1);
            acc2 = fmaf(m[(jj4 * 4 + 1) * 4 + 2], gv.y, acc2);
            acc3 = fmaf(m[(jj4 * 4 + 1) * 4 + 3], gv.y, acc3);
            acc0 = fmaf(m[(jj4 * 4 + 2) * 4 + 0], gv.z, acc0);
            acc1 = fmaf(m[(jj4 * 4 + 2) * 4 + 1], gv.z, acc1);
            acc2 = fmaf(m[(jj4 * 4 + 2) * 4 + 2], gv.z, acc2);
            acc3 = fmaf(m[(jj4 * 4 + 2) * 4 + 3], gv.z, acc3);
            acc0 = fmaf(m[(jj4 * 4 + 3) * 4 + 0], gv.w, acc0);
            acc1 = fmaf(m[(jj4 * 4 + 3) * 4 + 1], gv.w, acc1);
            acc2 = fmaf(m[(jj4 * 4 + 3) * 4 + 2], gv.w, acc2);
            acc3 = fmaf(m[(jj4 * 4 + 3) * 4 + 3], gv.w, acc3);
        }
        float part = fmaf(acc0, s4.x, fmaf(acc1, s4.y, fmaf(acc2, s4.z, acc3 * s4.w)));
        part_lds[tid] = part;
        __syncthreads();

        if (tid < RPW) {
            float hn = uval;
#pragma unroll
            for (int p = 0; p < 8; ++p) hn += part_lds[tid + 32 * p];
            out[(size_t)(b * L_DIM + t) * H_DIM + slice * RPW + tid] = hn;
            unsigned long long pw = ((unsigned long long)(unsigned int)(t + 1) << 32) |
                                    (unsigned long long)__float_as_uint(hn);
            __hip_atomic_store(hb + (size_t)((t + 1) & 1) * (16 * 256) + b * 256 + slice * RPW + tid,
                               pw, __ATOMIC_RELAXED, __HIP_MEMORY_SCOPE_AGENT);
        }
        // no trailing barrier: part_lds is next written only after the next
        // __syncthreads; g_lds readers all passed the part_lds barrier.
    }
}

extern "C" void kernel_launch(void* const* d_in, const int* in_sizes, int n_in,
                              void* d_out, int out_size, void* d_ws, size_t ws_size,
                              hipStream_t stream) {
    const float* x    = (const float*)d_in[0];  // (16,1024,512)
    const float* Wsel = (const float*)d_in[1];  // (4,512)
    const float* bsel = (const float*)d_in[2];  // (4,)
    const float* W_B  = (const float*)d_in[3];  // (256,512)
    const float* M    = (const float*)d_in[4];  // (256,256,4)
    float* out = (float*)d_out;                 // (16,1024,256)

    char* ws = (char*)d_ws;
    unsigned long long* hb = (unsigned long long*)(ws + OFF_HB);
    float* SEL = (float*)(ws + OFF_SEL);
    float* rN  = (float*)(ws + OFF_RN);

    k_init<<<1, 512, 0, stream>>>(hb);
    k_par<<<2048, 256, 0, stream>>>(x, Wsel, bsel, W_B, M, SEL, rN, out);
    k_scan<<<B_DIM * SLICES, 256, 0, stream>>>(M, SEL, rN, out, hb);
}

// Round 9
// 1276.096 us; speedup vs baseline: 1.4498x; 1.0388x over previous
//
#include <hip/hip_runtime.h>

#define B_DIM 16
#define L_DIM 1024
#define D_DIM 512
#define H_DIM 256
#define K_DIM 4

#define SLICES 8        // wgs per batch
#define RPW 32          // rows per wg (H_DIM / SLICES)

// ---------------- workspace layout (bytes) ----------------
#define OFF_HB  0                      // u64 hb[2][16][256] (tag<<32 | f32 bits), 64KB
#define OFF_SEL 65536                  // float SEL[16384*4]
#define OFF_RN  327680                 // float rN[16384*256]

__device__ __forceinline__ float fast_log2(float x) { return __builtin_amdgcn_logf(x); }
__device__ __forceinline__ float fast_exp2(float x) { return __builtin_amdgcn_exp2f(x); }

// ---------------- fused parallel phase ----------------
// blocks [0,1024): norm-role  -- inline selector+softmax for its 16 t's,
//                  writes SEL, then rN (Lp column norms).
// blocks [1024,2048): u-role  -- 64x64 f32 GEMM tile of U = X @ W_B^T into out.
// block 2048: init-role       -- zeroes the tagged h state (replaces k_init).
#define GBM 64
#define GBN 64
#define GBK 32
__global__ __launch_bounds__(256) void k_par(const float* __restrict__ x,
                                             const float* __restrict__ Wsel,
                                             const float* __restrict__ bsel,
                                             const float* __restrict__ W_B,
                                             const float* __restrict__ M,
                                             float* __restrict__ SEL,
                                             float* __restrict__ rN,
                                             float* __restrict__ out,
                                             unsigned long long* __restrict__ hb) {
    __shared__ float Xs[GBK][GBM + 1];
    __shared__ float Ws[GBK][GBN + 1];
    __shared__ float4 sel_lds[16];
    const int bid = blockIdx.x;
    const int tid = threadIdx.x;

    if (bid >= 2048) {
        // ---------- init role ----------
        for (int i = tid; i < 2 * 16 * 256; i += 256) hb[i] = 0ull;
        return;
    }

    if (bid < 1024) {
        // ---------- norm role ----------
        const int b = bid >> 6;
        const int t0 = (bid & 63) << 4;
        const int lane = tid & 63;
        const int wv = tid >> 6;
        const float4* w4 = (const float4*)Wsel;
#pragma unroll
        for (int rr = 0; rr < 4; ++rr) {
            const int tt = wv * 4 + rr;
            const int row = b * L_DIM + t0 + tt;
            const float4* x4 = (const float4*)(x + (size_t)row * D_DIM);
            float4 xa = x4[lane * 2], xb = x4[lane * 2 + 1];
            float acc[4];
#pragma unroll
            for (int k = 0; k < 4; ++k) {
                float4 wa = w4[k * (D_DIM / 4) + lane * 2];
                float4 wb = w4[k * (D_DIM / 4) + lane * 2 + 1];
                acc[k] = xa.x * wa.x + xa.y * wa.y + xa.z * wa.z + xa.w * wa.w +
                         xb.x * wb.x + xb.y * wb.y + xb.z * wb.z + xb.w * wb.w;
            }
#pragma unroll
            for (int off = 1; off < 64; off <<= 1) {
#pragma unroll
                for (int k = 0; k < 4; ++k) acc[k] += __shfl_xor(acc[k], off, 64);
            }
            if (lane == 0) {
                float z[4], mx = -1e30f;
#pragma unroll
                for (int k = 0; k < 4; ++k) { z[k] = acc[k] + bsel[k]; mx = fmaxf(mx, z[k]); }
                float e[4], s = 0.0f;
#pragma unroll
                for (int k = 0; k < 4; ++k) { e[k] = fast_exp2((z[k] - mx) * 1.4426950408889634f); s += e[k]; }
                float inv = 1.0f / s;
                float4 o = { e[0] * inv, e[1] * inv, e[2] * inv, e[3] * inv };
                sel_lds[tt] = o;
                ((float4*)SEL)[row] = o;
            }
        }
        __syncthreads();

        const int j = tid;
        float s[16][4];
#pragma unroll
        for (int tt = 0; tt < 16; ++tt) {
            float4 sv = sel_lds[tt];
            s[tt][0] = sv.x; s[tt][1] = sv.y; s[tt][2] = sv.z; s[tt][3] = sv.w;
        }
        float acc[16] = {};
        const float4* M4 = (const float4*)M;
        for (int i = 0; i < H_DIM; ++i) {
            float4 m = M4[i * H_DIM + j];
#pragma unroll
            for (int tt = 0; tt < 16; ++tt) {
                float a = fmaf(m.x, s[tt][0], fmaf(m.y, s[tt][1],
                          fmaf(m.z, s[tt][2], m.w * s[tt][3])));
                a = fabsf(a);
                acc[tt] += fast_exp2(1.2f * fast_log2(a));  // |a|^1.2
            }
        }
#pragma unroll
        for (int tt = 0; tt < 16; ++tt) {
            rN[(size_t)(b * L_DIM + t0 + tt) * H_DIM + j] =
                fast_exp2(-0.8333333333f * fast_log2(acc[tt]));
        }
    } else {
        // ---------- u role: 64x64 f32 GEMM tile ----------
        const int w = bid - 1024;
        const int cb = (w & 3) * GBN;
        const int rb = (w >> 2) * GBM;
        const int tr = tid >> 4, tc = tid & 15;
        const int lrow = tid >> 2;
        const int lcol = (tid & 3) * 8;
        float acc[4][4] = {};
        for (int kt = 0; kt < D_DIM; kt += GBK) {
            float4 xa = *(const float4*)(x + (size_t)(rb + lrow) * D_DIM + kt + lcol);
            float4 xb = *(const float4*)(x + (size_t)(rb + lrow) * D_DIM + kt + lcol + 4);
            float4 wa = *(const float4*)(W_B + (size_t)(cb + lrow) * D_DIM + kt + lcol);
            float4 wb = *(const float4*)(W_B + (size_t)(cb + lrow) * D_DIM + kt + lcol + 4);
            __syncthreads();
            Xs[lcol + 0][lrow] = xa.x; Xs[lcol + 1][lrow] = xa.y;
            Xs[lcol + 2][lrow] = xa.z; Xs[lcol + 3][lrow] = xa.w;
            Xs[lcol + 4][lrow] = xb.x; Xs[lcol + 5][lrow] = xb.y;
            Xs[lcol + 6][lrow] = xb.z; Xs[lcol + 7][lrow] = xb.w;
            Ws[lcol + 0][lrow] = wa.x; Ws[lcol + 1][lrow] = wa.y;
            Ws[lcol + 2][lrow] = wa.z; Ws[lcol + 3][lrow] = wa.w;
            Ws[lcol + 4][lrow] = wb.x; Ws[lcol + 5][lrow] = wb.y;
            Ws[lcol + 6][lrow] = wb.z; Ws[lcol + 7][lrow] = wb.w;
            __syncthreads();
#pragma unroll
            for (int kk = 0; kk < GBK; ++kk) {
                float a0 = Xs[kk][tr * 4 + 0], a1 = Xs[kk][tr * 4 + 1];
                float a2 = Xs[kk][tr * 4 + 2], a3 = Xs[kk][tr * 4 + 3];
                float b0 = Ws[kk][tc * 4 + 0], b1 = Ws[kk][tc * 4 + 1];
                float b2 = Ws[kk][tc * 4 + 2], b3 = Ws[kk][tc * 4 + 3];
                acc[0][0] = fmaf(a0, b0, acc[0][0]); acc[0][1] = fmaf(a0, b1, acc[0][1]);
                acc[0][2] = fmaf(a0, b2, acc[0][2]); acc[0][3] = fmaf(a0, b3, acc[0][3]);
                acc[1][0] = fmaf(a1, b0, acc[1][0]); acc[1][1] = fmaf(a1, b1, acc[1][1]);
                acc[1][2] = fmaf(a1, b2, acc[1][2]); acc[1][3] = fmaf(a1, b3, acc[1][3]);
                acc[2][0] = fmaf(a2, b0, acc[2][0]); acc[2][1] = fmaf(a2, b1, acc[2][1]);
                acc[2][2] = fmaf(a2, b2, acc[2][2]); acc[2][3] = fmaf(a2, b3, acc[2][3]);
                acc[3][0] = fmaf(a3, b0, acc[3][0]); acc[3][1] = fmaf(a3, b1, acc[3][1]);
                acc[3][2] = fmaf(a3, b2, acc[3][2]); acc[3][3] = fmaf(a3, b3, acc[3][3]);
            }
            __syncthreads();
        }
#pragma unroll
        for (int mi = 0; mi < 4; ++mi) {
            float4 v = { acc[mi][0], acc[mi][1], acc[mi][2], acc[mi][3] };
            *(float4*)(out + (size_t)(rb + tr * 4 + mi) * H_DIM + cb + tc * 4) = v;
        }
    }
}

// ---------------- sequential scan (tagged-word sync, single barrier) ----------------
// 128 wgs: b = wg&15, slice = wg>>4. Tagged 64-bit words: poll IS the data load.
// Wave q writes AND reads only g_lds[q*64 .. q*64+64) -> no barrier needed
// before the FMA loop (wave-synchronous LDS, lgkmcnt ordering). part_lds is
// parity-double-buffered: with one barrier/step a wave is at most one step
// ahead, so same-parity clobber is impossible. Wave 0 publishes all 32 rows
// as one contiguous burst (R5-proven pattern).
__global__ __launch_bounds__(256, 1) void k_scan(const float* __restrict__ M,
                                                 const float* __restrict__ SEL,
                                                 const float* __restrict__ rN,
                                                 float* __restrict__ out,
                                                 unsigned long long* hb) {
    const int wg = blockIdx.x;
    const int b = wg & 15;
    const int slice = wg >> 4;
    const int tid = threadIdx.x;
    const int q = tid >> 6;
    const int ti = tid & 63;
    const int r = ti & 31;
    const int js = ti >> 5;
    const int ig = slice * RPW + r;
    const int jbase = q * 64 + js * 32;

    float m[128];
    {
        const float4* M4 = (const float4*)M;
#pragma unroll
        for (int jj = 0; jj < 32; ++jj) {
            float4 v = M4[ig * H_DIM + jbase + jj];
            m[jj * 4 + 0] = v.x; m[jj * 4 + 1] = v.y;
            m[jj * 4 + 2] = v.z; m[jj * 4 + 3] = v.w;
        }
    }

    __shared__ float g_lds[256];
    __shared__ float part_lds[2][256];

#pragma unroll 1
    for (int t = 0; t < L_DIM; ++t) {
        // independent loads issued before the poll (latency hidden under it)
        float rn = rN[(size_t)(b * L_DIM + t) * H_DIM + tid];
        float4 s4 = ((const float4*)SEL)[b * L_DIM + t];
        float uval = 0.0f;
        if (tid < RPW) uval = out[(size_t)(b * L_DIM + t) * H_DIM + slice * RPW + tid];

        // poll own tagged word for step t (thread tid <-> column j = tid)
        unsigned long long* src = hb + (size_t)(t & 1) * (16 * 256) + b * 256 + tid;
        unsigned long long w;
        while (((w = __hip_atomic_load(src, __ATOMIC_RELAXED, __HIP_MEMORY_SCOPE_AGENT)) >> 32)
               != (unsigned int)t) { }
        float h = __uint_as_float((unsigned int)w);
        g_lds[tid] = h * rn;   // wave-local region; no barrier needed

        float acc0 = 0, acc1 = 0, acc2 = 0, acc3 = 0;
        const float4* g4 = (const float4*)(g_lds + jbase);
#pragma unroll
        for (int jj4 = 0; jj4 < 8; ++jj4) {
            float4 gv = g4[jj4];
            acc0 = fmaf(m[(jj4 * 4 + 0) * 4 + 0], gv.x, acc0);
            acc1 = fmaf(m[(jj4 * 4 + 0) * 4 + 1], gv.x, acc1);
            acc2 = fmaf(m[(jj4 * 4 + 0) * 4 + 2], gv.x, acc2);
            acc3 = fmaf(m[(jj4 * 4 + 0) * 4 + 3], gv.x, acc3);
            acc0 = fmaf(m[(jj4 * 4 + 1) * 4 + 0], gv.y, acc0);
            acc1 = fmaf(m[(jj4 * 4 + 1) * 4 + 1], gv.y, acc1);
            acc2 = fmaf(m[(jj4 * 4 + 1) * 4 + 2], gv.y, acc2);
            acc3 = fmaf(m[(jj4 * 4 + 1) * 4 + 3], gv.y, acc3);
            acc0 = fmaf(m[(jj4 * 4 + 2) * 4 + 0], gv.z, acc0);
            acc1 = fmaf(m[(jj4 * 4 + 2) * 4 + 1], gv.z, acc1);
            acc2 = fmaf(m[(jj4 * 4 + 2) * 4 + 2], gv.z, acc2);
            acc3 = fmaf(m[(jj4 * 4 + 2) * 4 + 3], gv.z, acc3);
            acc0 = fmaf(m[(jj4 * 4 + 3) * 4 + 0], gv.w, acc0);
            acc1 = fmaf(m[(jj4 * 4 + 3) * 4 + 1], gv.w, acc1);
            acc2 = fmaf(m[(jj4 * 4 + 3) * 4 + 2], gv.w, acc2);
            acc3 = fmaf(m[(jj4 * 4 + 3) * 4 + 3], gv.w, acc3);
        }
        float part = fmaf(acc0, s4.x, fmaf(acc1, s4.y, fmaf(acc2, s4.z, acc3 * s4.w)));
        part_lds[t & 1][tid] = part;
        __syncthreads();

        if (tid < RPW) {
            float hn = uval;
#pragma unroll
            for (int p = 0; p < 8; ++p) hn += part_lds[t & 1][tid + 32 * p];
            unsigned long long pw = ((unsigned long long)(unsigned int)(t + 1) << 32) |
                                    (unsigned long long)__float_as_uint(hn);
            __hip_atomic_store(hb + (size_t)((t + 1) & 1) * (16 * 256) + b * 256 + slice * RPW + tid,
                               pw, __ATOMIC_RELAXED, __HIP_MEMORY_SCOPE_AGENT);
            out[(size_t)(b * L_DIM + t) * H_DIM + slice * RPW + tid] = hn;
        }
    }
}

extern "C" void kernel_launch(void* const* d_in, const int* in_sizes, int n_in,
                              void* d_out, int out_size, void* d_ws, size_t ws_size,
                              hipStream_t stream) {
    const float* x    = (const float*)d_in[0];  // (16,1024,512)
    const float* Wsel = (const float*)d_in[1];  // (4,512)
    const float* bsel = (const float*)d_in[2];  // (4,)
    const float* W_B  = (const float*)d_in[3];  // (256,512)
    const float* M    = (const float*)d_in[4];  // (256,256,4)
    float* out = (float*)d_out;                 // (16,1024,256)

    char* ws = (char*)d_ws;
    unsigned long long* hb = (unsigned long long*)(ws + OFF_HB);
    float* SEL = (float*)(ws + OFF_SEL);
    float* rN  = (float*)(ws + OFF_RN);

    k_par<<<2049, 256, 0, stream>>>(x, Wsel, bsel, W_B, M, SEL, rN, out, hb);
    k_scan<<<B_DIM * SLICES, 256, 0, stream>>>(M, SEL, rN, out, hb);
}